// Round 11
// baseline (181.826 us; speedup 1.0000x reference)
//
#include <hip/hip_runtime.h>
#include <hip/hip_bf16.h>

typedef __attribute__((ext_vector_type(8))) __bf16 bf16x8;
typedef __attribute__((ext_vector_type(4))) float f32x4;

#define HID 1024      // H
#define FD  768       // F (K of first GEMM)
#define MR  8192      // B*E == B*D rows
#define BM  256
#define BN  128
#define BK  32
#define KSTEPS (FD / BK)   // 24

#define GLOAD_LDS16(g, l)                                                  \
    __builtin_amdgcn_global_load_lds(                                      \
        (const __attribute__((address_space(1))) unsigned int*)(g),        \
        (__attribute__((address_space(3))) unsigned int*)(l), 16, 0, 0)

// ---------------------------------------------------------------------------
// f32 -> bf16 conversion pass (Xe, Xd, We, Wd), 8 elems/thread  [R9 verbatim]
// ---------------------------------------------------------------------------
__global__ __launch_bounds__(256)
void cvt_kernel(const float* __restrict__ se, const float* __restrict__ sd,
                const float* __restrict__ swe, const float* __restrict__ swd,
                __bf16* __restrict__ de, __bf16* __restrict__ dd,
                __bf16* __restrict__ dwe, __bf16* __restrict__ dwd)
{
    const int blk = blockIdx.x;
    const float* __restrict__ src;
    __bf16* __restrict__ dst;
    long base;
    if (blk < 3072)      { src = se;  dst = de;  base = (long)blk * 2048; }
    else if (blk < 6144) { src = sd;  dst = dd;  base = (long)(blk - 3072) * 2048; }
    else if (blk < 6528) { src = swe; dst = dwe; base = (long)(blk - 6144) * 2048; }
    else                 { src = swd; dst = dwd; base = (long)(blk - 6528) * 2048; }
    const long i = base + (long)threadIdx.x * 8;
    const float4 a = *reinterpret_cast<const float4*>(src + i);
    const float4 b = *reinterpret_cast<const float4*>(src + i + 4);
    bf16x8 w;
    w[0] = (__bf16)a.x; w[1] = (__bf16)a.y; w[2] = (__bf16)a.z; w[3] = (__bf16)a.w;
    w[4] = (__bf16)b.x; w[5] = (__bf16)b.y; w[6] = (__bf16)b.z; w[7] = (__bf16)b.w;
    *reinterpret_cast<bf16x8*>(dst + i) = w;
}

// ---------------------------------------------------------------------------
// Fused GEMM+proj: 256x128 tile, BK=32, 8 waves (wr=wid>>1 rows, wc=wid&1 cols,
// 64x64 per wave). Same proven 2-phase prefetch loop + gload_lds staging
// pattern as R9, scaled. Epilogue: 16-lane shfl reduce -> red[256][2] slots
// (each written exactly once) -> 256 threads do masked global atomics.
// ---------------------------------------------------------------------------
__global__ __launch_bounds__(512, 2)
void gemm_proj_kernel(const __bf16* __restrict__ Xe, const __bf16* __restrict__ Xd,
                      const __bf16* __restrict__ We, const __bf16* __restrict__ Wd,
                      const float* __restrict__ me, const float* __restrict__ md,
                      const float* __restrict__ be, const float* __restrict__ bd,
                      const float* __restrict__ W1,
                      float* __restrict__ pe, float* __restrict__ pd)
{
    const int z = blockIdx.z;
    const __bf16* __restrict__ X    = z ? Xd : Xe;
    const __bf16* __restrict__ Wt   = z ? Wd : We;
    const float* __restrict__ bias  = z ? bd : be;
    const float* __restrict__ msk   = z ? md : me;
    float* __restrict__ proj        = z ? pd : pe;
    const int w1off = z ? 0 : HID;

    __shared__ union {
        struct { __bf16 A[2][BM][BK]; __bf16 B[2][BN][BK]; } st;  // 32+16 KB
        f32x4 red[BM][2];                                         // 8 KB
    } sm;

    const int t    = threadIdx.x;        // 0..511
    const int lane = t & 63;
    const int wid  = t >> 6;             // 0..7
    const int wr   = wid >> 1;           // 0..3  (64-row band)
    const int wc   = wid & 1;            // 0..1  (64-col band)
    const int l15  = lane & 15;
    const int l4   = lane >> 4;

    const long m0 = (long)blockIdx.x * BM;
    const int  n0 = blockIdx.y * BN;

    f32x4 acc[4][4];
    #pragma unroll
    for (int i = 0; i < 4; ++i)
        #pragma unroll
        for (int j = 0; j < 4; ++j)
            acc[i][j] = (f32x4){0.f, 0.f, 0.f, 0.f};

    // staging: wave wid stages A rows [wid*32,+32) (2 issues x 16 rows) and
    // B rows [wid*16,+16) (1 issue). lane -> row srow=lane>>2, 16B chunk lane&3.
    const int srow = lane >> 2;
    const int scol = (lane & 3) * 8;
    const __bf16* ga = X  + (m0 + wid*32 + srow) * (long)FD + scol;
    const __bf16* gb = Wt + (long)(n0 + wid*16 + srow) * FD + scol;

#define STAGE(p, ks) do {                                                  \
        const int k0_ = (ks) * BK;                                         \
        GLOAD_LDS16(ga + k0_,               &sm.st.A[p][wid*32 +  0][0]);  \
        GLOAD_LDS16(ga + (long)16*FD + k0_, &sm.st.A[p][wid*32 + 16][0]);  \
        GLOAD_LDS16(gb + k0_,               &sm.st.B[p][wid*16][0]);       \
    } while (0)

    STAGE(0, 0);
    __syncthreads();

    int cur = 0;
    for (int ks = 0; ks < KSTEPS; ++ks) {
        if (ks + 1 < KSTEPS) STAGE(cur ^ 1, ks + 1);   // prefetch next tile

        bf16x8 af[4], bfr[4];
        #pragma unroll
        for (int m = 0; m < 4; ++m)
            af[m] = *reinterpret_cast<const bf16x8*>(&sm.st.A[cur][wr*64 + m*16 + l15][l4*8]);
        #pragma unroll
        for (int n = 0; n < 4; ++n)
            bfr[n] = *reinterpret_cast<const bf16x8*>(&sm.st.B[cur][wc*64 + n*16 + l15][l4*8]);

        #pragma unroll
        for (int m = 0; m < 4; ++m)
            #pragma unroll
            for (int n = 0; n < 4; ++n)
                acc[m][n] = __builtin_amdgcn_mfma_f32_16x16x32_bf16(
                                af[m], bfr[n], acc[m][n], 0, 0, 0);

        __syncthreads();   // stage landed (vmcnt) + reads done; swap-safe
        cur ^= 1;
    }

    // ---- epilogue: bias+relu, dot 3 W1 rows, shfl-reduce, slot write ----
    float bh[4], w1c0[4], w1c1[4], w1c2[4];
    #pragma unroll
    for (int n = 0; n < 4; ++n) {
        int h = n0 + wc*64 + n*16 + l15;
        bh[n]   = bias[h];
        w1c0[n] = W1[0*2*HID + w1off + h];
        w1c1[n] = W1[1*2*HID + w1off + h];
        w1c2[n] = W1[2*2*HID + w1off + h];
    }

    #pragma unroll
    for (int m = 0; m < 4; ++m) {
        #pragma unroll
        for (int r = 0; r < 4; ++r) {
            float p0 = 0.f, p1 = 0.f, p2 = 0.f;
            #pragma unroll
            for (int n = 0; n < 4; ++n) {
                float s = fmaxf(acc[m][n][r] + bh[n], 0.f);
                p0 = fmaf(s, w1c0[n], p0);
                p1 = fmaf(s, w1c1[n], p1);
                p2 = fmaf(s, w1c2[n], p2);
            }
            // sum the wave's 64 cols: reduce over the 16 l15-lanes
            #pragma unroll
            for (int off = 1; off < 16; off <<= 1) {
                p0 += __shfl_xor(p0, off);
                p1 += __shfl_xor(p1, off);
                p2 += __shfl_xor(p2, off);
            }
            if (l15 == 0)
                sm.red[wr*64 + m*16 + l4*4 + r][wc] = (f32x4){p0, p1, p2, 0.f};
        }
    }
    __syncthreads();

    if (t < BM) {
        f32x4 s = sm.red[t][0] + sm.red[t][1];
        const long grow = m0 + t;
        const float mk = msk[grow];
        atomicAdd(&proj[grow*3+0], s.x * mk);
        atomicAdd(&proj[grow*3+1], s.y * mk);
        atomicAdd(&proj[grow*3+2], s.z * mk);
    }
#undef STAGE
}

// ---------------------------------------------------------------------------
// loss: 2048 blocks; block = 4 consecutive d rows of one b.  [R9 verbatim]
// ---------------------------------------------------------------------------
__global__ __launch_bounds__(256)
void loss_kernel(const float* __restrict__ pe, const float* __restrict__ pd,
                 const float* __restrict__ b1, const int* __restrict__ labels,
                 float* __restrict__ psum, float* __restrict__ pcnt)
{
    const int g = blockIdx.x;            // 0..2047
    const int b = g >> 8;
    const int dbase = (g & 255) * 4;
    const int t = threadIdx.x;
    const int e0 = t * 4;

    const float4* pep = reinterpret_cast<const float4*>(pe + ((long)b*1024 + e0)*3);
    float4 q0 = pep[0], q1 = pep[1], q2 = pep[2];
    float epv[12] = {q0.x,q0.y,q0.z,q0.w, q1.x,q1.y,q1.z,q1.w, q2.x,q2.y,q2.z,q2.w};

    float lsum = 0.f, lcnt = 0.f;
    #pragma unroll
    for (int r = 0; r < 4; ++r) {
        const long bd = (long)b*1024 + dbase + r;
        const float d0 = pd[bd*3+0] + b1[0];
        const float d1 = pd[bd*3+1] + b1[1];
        const float d2 = pd[bd*3+2] + b1[2];
        const int4 lb = *reinterpret_cast<const int4*>(labels + bd*1024 + e0);
        const int lv[4] = {lb.x, lb.y, lb.z, lb.w};
        #pragma unroll
        for (int i = 0; i < 4; ++i) {
            float l0 = d0 + epv[i*3+0];
            float l1 = d1 + epv[i*3+1];
            float l2 = d2 + epv[i*3+2];
            float mx  = fmaxf(l0, fmaxf(l1, l2));
            float lse = mx + __logf(__expf(l0-mx) + __expf(l1-mx) + __expf(l2-mx));
            int la = lv[i];
            if (la != -100) {
                float sel = (la == 0) ? l0 : ((la == 1) ? l1 : l2);
                lsum += lse - sel;
                lcnt += 1.f;
            }
        }
    }
    #pragma unroll
    for (int off = 1; off < 64; off <<= 1) {
        lsum += __shfl_xor(lsum, off);
        lcnt += __shfl_xor(lcnt, off);
    }
    __shared__ float shs[4], shc[4];
    const int wv = t >> 6;
    if ((t & 63) == 0) { shs[wv] = lsum; shc[wv] = lcnt; }
    __syncthreads();
    if (t == 0) {
        psum[g] = shs[0]+shs[1]+shs[2]+shs[3];
        pcnt[g] = shc[0]+shc[1]+shc[2]+shc[3];
    }
}

__global__ __launch_bounds__(256)
void finalize_kernel(const float* __restrict__ psum, const float* __restrict__ pcnt,
                     float* __restrict__ out)
{
    const int t = threadIdx.x;
    float s = 0.f, c = 0.f;
    for (int i = t; i < 2048; i += 256) { s += psum[i]; c += pcnt[i]; }
    #pragma unroll
    for (int off = 1; off < 64; off <<= 1) {
        s += __shfl_xor(s, off);
        c += __shfl_xor(c, off);
    }
    __shared__ float shs[4], shc[4];
    const int wv = t >> 6;
    if ((t & 63) == 0) { shs[wv] = s; shc[wv] = c; }
    __syncthreads();
    if (t == 0)
        out[0] = (shs[0]+shs[1]+shs[2]+shs[3]) / fmaxf(shc[0]+shc[1]+shc[2]+shc[3], 1.0f);
}

// ---------------------------------------------------------------------------
extern "C" void kernel_launch(void* const* d_in, const int* in_sizes, int n_in,
                              void* d_out, int out_size, void* d_ws, size_t ws_size,
                              hipStream_t stream)
{
    (void)in_sizes; (void)n_in; (void)out_size; (void)ws_size;

    const float* enc   = (const float*)d_in[0];
    const float* dec   = (const float*)d_in[1];   // (1,B,D,F) -> base ptr
    const float* maske = (const float*)d_in[2];
    const float* maskd = (const float*)d_in[3];
    const float* We    = (const float*)d_in[4];
    const float* be    = (const float*)d_in[5];
    const float* Wd    = (const float*)d_in[6];
    const float* bd    = (const float*)d_in[7];
    const float* W1    = (const float*)d_in[8];
    const float* b1    = (const float*)d_in[9];
    const int*   labels= (const int*)d_in[10];

    float* pe   = (float*)d_ws;                   // 3*MR
    float* pd   = pe + 3*MR;                      // 3*MR
    float* psum = pd + 3*MR;                      // 2048
    float* pcnt = psum + MR;                      // 2048
    __bf16* Xeb = (__bf16*)(pcnt + MR);           // MR*FD
    __bf16* Xdb = Xeb + (long)MR*FD;              // MR*FD
    __bf16* Web = Xdb + (long)MR*FD;              // HID*FD
    __bf16* Wdb = Web + (long)HID*FD;             // HID*FD

    hipMemsetAsync(d_ws, 0, (size_t)(6*MR) * sizeof(float), stream);

    cvt_kernel<<<6912, 256, 0, stream>>>(enc, dec, We, Wd, Xeb, Xdb, Web, Wdb);

    dim3 grid(MR/BM, HID/BN, 2);
    gemm_proj_kernel<<<grid, 512, 0, stream>>>(Xeb, Xdb, Web, Wdb,
                                               maske, maskd, be, bd, W1, pe, pd);
    loss_kernel<<<2048, 256, 0, stream>>>(pe, pd, b1, labels, psum, pcnt);
    finalize_kernel<<<1, 256, 0, stream>>>(psum, pcnt, (float*)d_out);
}